// Round 22
// baseline (120.994 us; speedup 1.0000x reference)
//
#include <hip/hip_runtime.h>
#include <stdint.h>

#define NB 2
#define NS 2048
#define ND 1024
#define NH 16
#define NDK 64

typedef __attribute__((ext_vector_type(8))) short s8v;
typedef __attribute__((ext_vector_type(4))) float f4v;
typedef __attribute__((ext_vector_type(4))) unsigned short us4v;
typedef __attribute__((ext_vector_type(8))) unsigned short us8v;
typedef __attribute__((ext_vector_type(2))) uint32_t u2v;
typedef __attribute__((ext_vector_type(4))) uint32_t u4v;

__device__ __forceinline__ unsigned short f2bf(float f) {
  uint32_t u = __builtin_bit_cast(uint32_t, f);
  u = (u + 0x7fffu + ((u >> 16) & 1u)) >> 16;
  return (unsigned short)u;
}
__device__ __forceinline__ float bf2f(unsigned short h) {
  uint32_t u = ((uint32_t)h) << 16;
  return __builtin_bit_cast(float, u);
}
// packed f32x2 -> bf16x2 (lo -> bits[15:0]), RNE
__device__ __forceinline__ uint32_t cvtpk(float lo, float hi) {
  uint32_t r;
  asm("v_cvt_pk_bf16_f32 %0, %1, %2" : "=v"(r) : "v"(lo), "v"(hi));
  return r;
}
__device__ __forceinline__ float max3f(float a, float b, float c) {
  float r;
  asm("v_max3_f32 %0, %1, %2, %3" : "=v"(r) : "v"(a), "v"(b), "v"(c));
  return r;
}

__device__ __forceinline__ void gload16(const void* g, void* l) {
  __builtin_amdgcn_global_load_lds(
      (const __attribute__((address_space(1))) void*)g,
      (__attribute__((address_space(3))) void*)l, 16, 0, 0);
}

// ------------------------------------------- fused convert x + transpose W
__global__ void k_prep(const float* __restrict__ x, unsigned short* __restrict__ xbf,
                       const float* __restrict__ Wq, const float* __restrict__ Wk,
                       const float* __restrict__ Wv, const float* __restrict__ Wo,
                       unsigned short* __restrict__ wt_qkv, unsigned short* __restrict__ wt_o) {
  __shared__ float tls[64][65];
  if (blockIdx.x < 4096) {
    int i = (blockIdx.x * 256 + threadIdx.x) * 4;
    float4 v = *(const float4*)(x + i);
    us4v o;
    o[0] = f2bf(v.x); o[1] = f2bf(v.y); o[2] = f2bf(v.z); o[3] = f2bf(v.w);
    *(us4v*)(xbf + i) = o;
    return;
  }
  int bid = blockIdx.x - 4096;
  int mat = bid >> 8;
  int tile = bid & 255;
  int tk = tile >> 4, tn = tile & 15;
  const float* W = (mat == 0) ? Wq : (mat == 1) ? Wk : (mat == 2) ? Wv : Wo;
  int t = threadIdx.x;
  int lr = t >> 2;
  int lc0 = (t & 3) * 16;
  const float* src = W + (size_t)(tk * 64 + lr) * 1024 + tn * 64 + lc0;
#pragma unroll
  for (int j = 0; j < 16; j += 4) {
    float4 v = *(const float4*)(src + j);
    tls[lr][lc0 + j + 0] = v.x; tls[lr][lc0 + j + 1] = v.y;
    tls[lr][lc0 + j + 2] = v.z; tls[lr][lc0 + j + 3] = v.w;
  }
  __syncthreads();
  float scale = (mat == 0) ? 0.18033688f : 1.0f;  // 0.125 * 1/ln2
  int nr = t >> 2, kc0 = (t & 3) * 16;
  unsigned short* dst = ((mat < 3) ? (wt_qkv + (size_t)(mat * 1024 + tn * 64 + nr) * 1024)
                                   : (wt_o + (size_t)(tn * 64 + nr) * 1024)) + tk * 64 + kc0;
  us8v o0, o1;
#pragma unroll
  for (int j = 0; j < 8; j++) o0[j] = f2bf(tls[kc0 + j][nr] * scale);
#pragma unroll
  for (int j = 0; j < 8; j++) o1[j] = f2bf(tls[kc0 + 8 + j][nr] * scale);
  *(us8v*)(dst) = o0;
  *(us8v*)(dst + 8) = o1;
}

// --------------------------------------------------------------- QKV GEMM
// BK=32, FIVE-stage rotation (80KB, still exactly 2 WG/CU): stage S(kt+4)
// each iter; pre-barrier wait retires S(kt+1) issued THREE iterations ago
// (~3 periods of cover; R21's 2-period cover gained 4us but the awaited load
// was still in flight => queue-class latency >= 4000cy).  S(kt+2..4) = 12
// loads stay in flight across the barrier.  Tail: vmcnt(12)/(8)/(4)/(0).
__global__ __launch_bounds__(256) void k_gemm0(const unsigned short* __restrict__ A,
                                               const unsigned short* __restrict__ Bt,
                                               unsigned short* __restrict__ qklin,
                                               unsigned short* __restrict__ vt,
                                               float* __restrict__ vmean) {
  __shared__ unsigned short smem[10 * 128 * 32];  // 80KB: A bufs 0-4, B bufs 0-4
#define SA(b_) (smem + (b_)*4096)
#define SB(b_) (smem + 20480 + (b_)*4096)
  const int K = 1024;
  const int NT = K / 32;
  int bid = blockIdx.x;
  int xcd = bid & 7, local = bid >> 3;
  int m0 = ((xcd >> 1) * 8 + (local & 7)) * 128;   // R20 chunking (kept)
  int n0 = ((xcd & 1) * 12 + (local >> 3)) * 128;
  int tid = threadIdx.x, lane = tid & 63, w = tid >> 6;
  int wm = w >> 1, wn = w & 1;
  int g = lane >> 4, c0 = lane & 15;
  int rrel = lane >> 2;
  int gran = lane & 3;
  int rsw = (rrel >> 1) & 3;
  int csw = (c0 >> 1) & 3;
  f4v acc[4][4];
#pragma unroll
  for (int mi = 0; mi < 4; mi++)
#pragma unroll
    for (int ni = 0; ni < 4; ni++) acc[mi][ni] = (f4v){0.f, 0.f, 0.f, 0.f};

#define STAGE(kt_, buf_)                                                        \
  do {                                                                          \
    int koff = (kt_)*32;                                                        \
    _Pragma("unroll") for (int i = 0; i < 2; i++) {                             \
      int r = 32 * w + 16 * i + rrel;                                           \
      gload16(A + (size_t)(m0 + r) * K + koff + 8 * (gran ^ rsw),               \
              (void*)(SA(buf_) + (32 * w + 16 * i) * 32));                      \
      gload16(Bt + (size_t)(n0 + r) * K + koff + 8 * (gran ^ rsw),              \
              (void*)(SB(buf_) + (32 * w + 16 * i) * 32));                      \
    }                                                                           \
  } while (0)

  // prologue: 4 tiles in flight (16 loads/wave); retire S(0) -> vmcnt(12)
  STAGE(0, 0);
  STAGE(1, 1);
  STAGE(2, 2);
  STAGE(3, 3);
  asm volatile("s_waitcnt vmcnt(12)" ::: "memory");
  __builtin_amdgcn_s_barrier();
  __builtin_amdgcn_sched_barrier(0);

  for (int kt = 0; kt < NT; ++kt) {
    int cur = kt % 5;
    if (kt + 4 < NT) STAGE(kt + 4, (kt + 4) % 5);
    s8v af[4], bfr[4];
#pragma unroll
    for (int mi = 0; mi < 4; mi++) {
      int row = 64 * wm + 16 * mi + c0;
      af[mi] = *(const s8v*)(SA(cur) + row * 32 + 8 * (g ^ csw));
    }
#pragma unroll
    for (int ni = 0; ni < 4; ni++) {
      int row = 64 * wn + 16 * ni + c0;
      bfr[ni] = *(const s8v*)(SB(cur) + row * 32 + 8 * (g ^ csw));
    }
#pragma unroll
    for (int mi = 0; mi < 4; mi++)
#pragma unroll
      for (int ni = 0; ni < 4; ni++)
        acc[mi][ni] = __builtin_amdgcn_mfma_f32_16x16x32_bf16(af[mi], bfr[ni], acc[mi][ni], 0, 0, 0);
    if (kt + 1 < NT) {
      if (kt + 4 < NT) {
        asm volatile("s_waitcnt vmcnt(12)" ::: "memory");  // retire S(kt+1)
      } else if (kt + 3 < NT) {
        asm volatile("s_waitcnt vmcnt(8)" ::: "memory");
      } else if (kt + 2 < NT) {
        asm volatile("s_waitcnt vmcnt(4)" ::: "memory");
      } else {
        asm volatile("s_waitcnt vmcnt(0)" ::: "memory");
      }
      __builtin_amdgcn_s_barrier();
      __builtin_amdgcn_sched_barrier(0);
    }
  }
#undef STAGE

  if (n0 < 2048) {
#pragma unroll
    for (int mi = 0; mi < 4; mi++)
#pragma unroll
      for (int ni = 0; ni < 4; ni++)
#pragma unroll
        for (int r = 0; r < 4; r++) {
          int m = m0 + 64 * wm + 16 * mi + 4 * g + r;
          int n = n0 + 64 * wn + 16 * ni + c0;
          qklin[(size_t)m * 2048 + n] = f2bf(acc[mi][ni][r]);
        }
  } else {
    int bb = m0 >> 11;
#pragma unroll
    for (int ni = 0; ni < 4; ni++) {
      float s = 0.f;
#pragma unroll
      for (int mi = 0; mi < 4; mi++)
#pragma unroll
        for (int r = 0; r < 4; r++) s += acc[mi][ni][r];
      s += __shfl_xor(s, 16);
      s += __shfl_xor(s, 32);
      if ((lane >> 4) == 0) {
        int n = n0 + 64 * wn + 16 * ni + c0;
        int hh = (n - 2048) >> 6, dk = n & 63;
        atomicAdd(vmean + (bb * 16 + hh) * 64 + dk, s);
      }
    }
    const int PAD = 132;
    unsigned short* tl = smem;
    __syncthreads();
#pragma unroll
    for (int mi = 0; mi < 4; mi++)
#pragma unroll
      for (int ni = 0; ni < 4; ni++) {
        int nloc = 64 * wn + 16 * ni + c0;
        int m4 = 64 * wm + 16 * mi + 4 * g;
        us4v pk;
#pragma unroll
        for (int r = 0; r < 4; r++) pk[r] = f2bf(acc[mi][ni][r]);
        *(us4v*)(tl + nloc * PAD + m4) = pk;
      }
    __syncthreads();
    int row = tid >> 1, half = tid & 1;
    int n = n0 + row;
    int hh = (n - 2048) >> 6, dk = n & 63;
    int s0 = (m0 & 2047) + 64 * half;
    unsigned short* dstp = vt + (size_t)((bb * 16 + hh) * 64 + dk) * 2048 + s0;
    const unsigned short* srcp = tl + row * PAD + 64 * half;
#pragma unroll
    for (int j = 0; j < 8; j++) {
      us4v lo = *(const us4v*)(srcp + 8 * j);
      us4v hi = *(const us4v*)(srcp + 8 * j + 4);
      us8v v8;
      v8[0] = lo[0]; v8[1] = lo[1]; v8[2] = lo[2]; v8[3] = lo[3];
      v8[4] = hi[0]; v8[5] = hi[1]; v8[6] = hi[2]; v8[7] = hi[3];
      *(us8v*)(dstp + 8 * j) = v8;
    }
  }
#undef SA
#undef SB
}

// ------------------------------------------------------------ output GEMM
// 64x64 tiles, BK=64, 2-buf, 32KB LDS, 4 WG/CU (R20, proven).
__global__ __launch_bounds__(256) void k_gemm1(const unsigned short* __restrict__ A,
                                               const unsigned short* __restrict__ Bt,
                                               const float* __restrict__ bias,
                                               float* __restrict__ out) {
  __shared__ unsigned short lds_a[2][64 * 64];
  __shared__ unsigned short lds_b[2][64 * 64];
  const int K = 1024;
  const int NT = K / 64;
  int bid = blockIdx.x;
  int xcd = bid & 7, local = bid >> 3;
  int m0 = (xcd * 8 + (local & 7)) * 64;
  int n0 = (local >> 3) * 64;
  int tid = threadIdx.x, lane = tid & 63, w = tid >> 6;
  int wm = w >> 1, wn = w & 1;
  int g = lane >> 4, c0 = lane & 15;
  int rrel = lane >> 3;
  int gran = lane & 7;
  f4v acc[2][2];
#pragma unroll
  for (int mi = 0; mi < 2; mi++)
#pragma unroll
    for (int ni = 0; ni < 2; ni++) acc[mi][ni] = (f4v){0.f, 0.f, 0.f, 0.f};

#define STAGE1(kt_, buf_)                                                       \
  do {                                                                          \
    int koff = (kt_)*64;                                                        \
    _Pragma("unroll") for (int i = 0; i < 2; i++) {                             \
      int r = 16 * w + 8 * i + rrel;                                            \
      gload16(A + (size_t)(m0 + r) * K + koff + 8 * (gran ^ rrel),              \
              (void*)(lds_a[buf_] + (16 * w + 8 * i) * 64));                    \
      gload16(Bt + (size_t)(n0 + r) * K + koff + 8 * (gran ^ rrel),             \
              (void*)(lds_b[buf_] + (16 * w + 8 * i) * 64));                    \
    }                                                                           \
  } while (0)

  STAGE1(0, 0);
  __syncthreads();

  for (int kt = 0; kt < NT; ++kt) {
    int cur = kt & 1;
    if (kt + 1 < NT) STAGE1(kt + 1, cur ^ 1);
#pragma unroll
    for (int c = 0; c < 2; c++) {
      s8v af[2], bfr[2];
#pragma unroll
      for (int mi = 0; mi < 2; mi++) {
        int row = 32 * wm + 16 * mi + c0;
        af[mi] = *(const s8v*)(lds_a[cur] + row * 64 + 8 * ((g + 4 * c) ^ (c0 & 7)));
      }
#pragma unroll
      for (int ni = 0; ni < 2; ni++) {
        int row = 32 * wn + 16 * ni + c0;
        bfr[ni] = *(const s8v*)(lds_b[cur] + row * 64 + 8 * ((g + 4 * c) ^ (c0 & 7)));
      }
#pragma unroll
      for (int mi = 0; mi < 2; mi++)
#pragma unroll
        for (int ni = 0; ni < 2; ni++)
          acc[mi][ni] = __builtin_amdgcn_mfma_f32_16x16x32_bf16(af[mi], bfr[ni], acc[mi][ni], 0, 0, 0);
    }
    __syncthreads();
  }
#undef STAGE1

#pragma unroll
  for (int mi = 0; mi < 2; mi++)
#pragma unroll
    for (int ni = 0; ni < 2; ni++)
#pragma unroll
      for (int r = 0; r < 4; r++) {
        int m = m0 + 32 * wm + 16 * mi + 4 * g + r;
        int n = n0 + 32 * wn + 16 * ni + c0;
        out[(size_t)m * 1024 + n] = acc[mi][ni][r] + bias[n];
      }
}

// ------------------------------------------------------------ flash attention
// R19 version (proven 54.1us): pair-unrolled K-loop, compile-time cur/HASNEXT,
// causal mask only on the last tile, MFMA row-sum for l, v_max3 tree,
// defer-max (T13), exp2 softmax, counted vmcnt(5).
__global__ __launch_bounds__(256) void k_attn(const unsigned short* __restrict__ qklin,
                                              const unsigned short* __restrict__ vt,
                                              const int* __restrict__ kpm,
                                              const float* __restrict__ vmean,
                                              unsigned short* __restrict__ ctx) {
  __shared__ unsigned short lds_k[2][64 * 64];
  __shared__ unsigned short lds_v[2][64 * 64];
  __shared__ unsigned short p_lds[4][16 * 64];
  int wg = blockIdx.x;
  int w5 = wg >> 5, bh = wg & 31;
  int qt = (w5 < 8) ? 31 - w5 : (w5 < 16) ? w5 - 8 : (w5 < 24) ? 39 - w5 : w5 - 16;
  int b = bh >> 4, h = bh & 15;
  int tid = threadIdx.x, lane = tid & 63, w = tid >> 6;
  int g = lane >> 4, c0 = lane & 15;
  int q0 = qt * 64 + w * 16;
  unsigned short* pl = p_lds[w];
  int rrel = lane >> 3, gran = lane & 7;

  const unsigned short* ksrc0 = qklin + (size_t)(b * NS) * 2048 + 1024 + h * 64;
  const unsigned short* vsrc0 = vt + (size_t)(bh * 64) * 2048;

  const unsigned short* qbase = qklin + (size_t)(b * NS + q0 + c0) * 2048 + h * 64 + 8 * g;
  s8v qf0 = *(const s8v*)(qbase);
  s8v qf1 = *(const s8v*)(qbase + 32);

  const uint32_t one2 = 0x3F803F80u;
  u4v onesw = {one2, one2, one2, one2};
  s8v ones = __builtin_bit_cast(s8v, onesw);

  f4v cacc[4];
#pragma unroll
  for (int d = 0; d < 4; d++) cacc[d] = (f4v){0.f, 0.f, 0.f, 0.f};
  f4v lsum = (f4v){0.f, 0.f, 0.f, 0.f};
  float m_s = -1e30f;
  int qrow = q0 + c0;

#define STAGEKV(it_, buf_)                                                      \
  do {                                                                          \
    int kb_ = (it_)*64;                                                         \
    _Pragma("unroll") for (int i = 0; i < 2; i++) {                             \
      int r = 16 * w + 8 * i + rrel;                                            \
      gload16(ksrc0 + (size_t)(kb_ + r) * 2048 + 8 * (gran ^ rrel),             \
              (void*)(lds_k[buf_] + (16 * w + 8 * i) * 64));                    \
      gload16(vsrc0 + (size_t)r * 2048 + kb_ + 8 * (gran ^ rrel),               \
              (void*)(lds_v[buf_] + (16 * w + 8 * i) * 64));                    \
    }                                                                           \
  } while (0)

#define ATTN_BODY(CUR, HASNEXT, FULLC)                                          \
  {                                                                             \
    int kb = it * 64;                                                           \
    int kp_next = 0;                                                            \
    if (HASNEXT) {                                                              \
      STAGEKV(it + 1, CUR ^ 1);                                                 \
      kp_next = kpm[b * NS + (it + 1) * 64 + lane];                             \
      asm volatile("s_waitcnt vmcnt(5)" ::: "memory");                          \
    } else {                                                                    \
      asm volatile("s_waitcnt vmcnt(0)" ::: "memory");                          \
    }                                                                           \
    __builtin_amdgcn_s_barrier();                                               \
    __builtin_amdgcn_sched_barrier(0);                                          \
    uint64_t padmask = __ballot(kp_cur != 0);                                   \
    f4v sacc[4];                                                                \
    _Pragma("unroll") for (int t = 0; t < 4; t++) {                             \
      int row = 16 * t + c0;                                                    \
      s8v kf0 = *(const s8v*)(lds_k[CUR] + row * 64 + 8 * (g ^ (c0 & 7)));      \
      s8v kf1 = *(const s8v*)(lds_k[CUR] + row * 64 + 8 * ((4 + g) ^ (c0 & 7)));\
      f4v z = (f4v){0.f, 0.f, 0.f, 0.f};                                        \
      z = __builtin_amdgcn_mfma_f32_16x16x32_bf16(kf0, qf0, z, 0, 0, 0);        \
      z = __builtin_amdgcn_mfma_f32_16x16x32_bf16(kf1, qf1, z, 0, 0, 0);        \
      sacc[t] = z;                                                              \
    }                                                                           \
    uint64_t valid;                                                             \
    if (FULLC) {                                                                \
      valid = ~padmask;                                                         \
    } else {                                                                    \
      int thr = qrow - kb;                                                      \
      uint64_t cmask = (thr >= 63) ? ~0ull : ((2ull << thr) - 1ull);            \
      valid = cmask & ~padmask;                                                 \
    }                                                                           \
    uint32_t vlo = (uint32_t)valid, vhi = (uint32_t)(valid >> 32);              \
    float p[4][4];                                                              \
    _Pragma("unroll") for (int t = 0; t < 4; t++) {                             \
      uint32_t half = (t & 2) ? vhi : vlo;                                      \
      uint32_t nib = (half >> (16 * (t & 1) + 4 * g)) & 0xFu;                   \
      _Pragma("unroll") for (int r = 0; r < 4; r++) {                           \
        float s = sacc[t][r];                                                   \
        s = ((nib >> r) & 1u) ? s : -1e30f;                                     \
        p[t][r] = s;                                                            \
      }                                                                         \
    }                                                                           \
    float a0 = max3f(p[0][0], p[0][1], p[0][2]);                                \
    float a1 = max3f(p[0][3], p[1][0], p[1][1]);                                \
    float a2 = max3f(p[1][2], p[1][3], p[2][0]);                                \
    float a3 = max3f(p[2][1], p[2][2], p[2][3]);                                \
    float a4 = max3f(p[3][0], p[3][1], p[3][2]);                                \
    float mx = fmaxf(max3f(a0, a1, a2), max3f(a3, a4, p[3][3]));                \
    mx = fmaxf(mx, __shfl_xor(mx, 16));                                         \
    mx = fmaxf(mx, __shfl_xor(mx, 32));                                         \
    if (!__all(mx <= m_s + 11.0f)) {                                            \
      float mnew = fmaxf(m_s, mx);                                              \
      float a = __builtin_exp2f(m_s - mnew);                                    \
      m_s = mnew;                                                               \
      int ybase = 20 * g;                                                       \
      _Pragma("unroll") for (int r = 0; r < 4; r++) {                           \
        float ar = __shfl(a, ybase + r);                                        \
        lsum[r] *= ar;                                                          \
        _Pragma("unroll") for (int d = 0; d < 4; d++) cacc[d][r] *= ar;         \
      }                                                                         \
    }                                                                           \
    _Pragma("unroll") for (int t = 0; t < 4; t++)                               \
      _Pragma("unroll") for (int r = 0; r < 4; r++)                             \
        p[t][r] = __builtin_exp2f(p[t][r] - m_s);                               \
    _Pragma("unroll") for (int t = 0; t < 4; t++) {                             \
      u2v pk;                                                                   \
      pk[0] = cvtpk(p[t][0], p[t][1]);                                          \
      pk[1] = cvtpk(p[t][2], p[t][3]);                                          \
      int gr = (2 * t + (g >> 1)) ^ (c0 & 7);                                   \
      *(u2v*)((char*)pl + c0 * 128 + gr * 16 + 8 * (g & 1)) = pk;               \
    }                                                                           \
    asm volatile("s_waitcnt lgkmcnt(0)" ::: "memory");                          \
    __builtin_amdgcn_sched_barrier(0);                                          \
    _Pragma("unroll") for (int c = 0; c < 2; c++) {                             \
      int off = c0 * 128 + 16 * g + 64 * c;                                     \
      off ^= (c0 & 7) << 4;                                                     \
      s8v pf = *(const s8v*)((const char*)pl + off);                            \
      _Pragma("unroll") for (int d = 0; d < 4; d++) {                           \
        int row = 16 * d + c0;                                                  \
        s8v vf = *(const s8v*)(lds_v[CUR] + row * 64 + 8 * ((4 * c + g) ^ (c0 & 7))); \
        cacc[d] = __builtin_amdgcn_mfma_f32_16x16x32_bf16(pf, vf, cacc[d], 0, 0, 0);  \
      }                                                                         \
      lsum = __builtin_amdgcn_mfma_f32_16x16x32_bf16(pf, ones, lsum, 0, 0, 0);  \
    }                                                                           \
    __builtin_amdgcn_s_barrier();                                               \
    __builtin_amdgcn_sched_barrier(0);                                          \
    kp_cur = kp_next;                                                           \
  }

  STAGEKV(0, 0);
  int kp_cur = kpm[b * NS + lane];

  int it = 0;
  while (it + 1 < qt) {
    ATTN_BODY(0, 1, 1);
    it++;
    ATTN_BODY(1, 1, 1);
    it++;
  }
  if (qt & 1) {
    ATTN_BODY(0, 1, 1);
    it++;
    ATTN_BODY(1, 0, 0);
  } else {
    ATTN_BODY(0, 0, 0);
  }
#undef ATTN_BODY
#undef STAGEKV

  float mq[4];
  {
    int ybase = 20 * g;
#pragma unroll
    for (int r = 0; r < 4; r++) mq[r] = __shfl(m_s, ybase + r);
  }
#pragma unroll
  for (int d = 0; d < 4; d++)
#pragma unroll
    for (int r = 0; r < 4; r++) {
      int q = q0 + 4 * g + r;
      float l = (mq[r] > -1e29f) ? lsum[r] : 0.f;
      float v = (l > 0.f) ? cacc[d][r] / l
                          : vmean[bh * 64 + 16 * d + c0] * (1.0f / 2048.0f);
      ctx[(size_t)(b * NS + q) * ND + h * 64 + 16 * d + c0] = f2bf(v);
    }
}

// ----------------------------------------------------------------------------
extern "C" void kernel_launch(void* const* d_in, const int* in_sizes, int n_in,
                              void* d_out, int out_size, void* d_ws, size_t ws_size,
                              hipStream_t stream) {
  const float* x  = (const float*)d_in[0];
  const int* kpm  = (const int*)d_in[2];
  const float* Wq = (const float*)d_in[3];
  const float* Wk = (const float*)d_in[4];
  const float* Wv = (const float*)d_in[5];
  const float* Wo = (const float*)d_in[6];
  const float* bo = (const float*)d_in[7];

  char* ws = (char*)d_ws;
  unsigned short* xbf   = (unsigned short*)(ws);
  unsigned short* wtqkv = (unsigned short*)(ws + 8u * 1024 * 1024);
  unsigned short* wto   = (unsigned short*)(ws + 14u * 1024 * 1024);
  unsigned short* vt    = (unsigned short*)(ws + 16u * 1024 * 1024);
  float* vmean          = (float*)(ws + 24u * 1024 * 1024);
  unsigned short* ctx   = xbf;
  unsigned short* qklin = (unsigned short*)d_out;

  hipMemsetAsync(vmean, 0, 2048 * sizeof(float), stream);
  k_prep<<<5120, 256, 0, stream>>>(x, xbf, Wq, Wk, Wv, Wo, wtqkv, wto);
  k_gemm0<<<768, 256, 0, stream>>>(xbf, wtqkv, qklin, vt, vmean);
  k_attn<<<1024, 256, 0, stream>>>(qklin, vt, kpm, vmean, ctx);
  k_gemm1<<<1024, 256, 0, stream>>>(ctx, wto, bo, (float*)d_out);
}

// Round 23
// 120.360 us; speedup vs baseline: 1.0053x; 1.0053x over previous
//
#include <hip/hip_runtime.h>
#include <stdint.h>

#define NB 2
#define NS 2048
#define ND 1024
#define NH 16
#define NDK 64

typedef __attribute__((ext_vector_type(8))) short s8v;
typedef __attribute__((ext_vector_type(4))) float f4v;
typedef __attribute__((ext_vector_type(4))) unsigned short us4v;
typedef __attribute__((ext_vector_type(8))) unsigned short us8v;
typedef __attribute__((ext_vector_type(2))) uint32_t u2v;
typedef __attribute__((ext_vector_type(4))) uint32_t u4v;

__device__ __forceinline__ unsigned short f2bf(float f) {
  uint32_t u = __builtin_bit_cast(uint32_t, f);
  u = (u + 0x7fffu + ((u >> 16) & 1u)) >> 16;
  return (unsigned short)u;
}
__device__ __forceinline__ float bf2f(unsigned short h) {
  uint32_t u = ((uint32_t)h) << 16;
  return __builtin_bit_cast(float, u);
}
// packed f32x2 -> bf16x2 (lo -> bits[15:0]), RNE
__device__ __forceinline__ uint32_t cvtpk(float lo, float hi) {
  uint32_t r;
  asm("v_cvt_pk_bf16_f32 %0, %1, %2" : "=v"(r) : "v"(lo), "v"(hi));
  return r;
}
__device__ __forceinline__ float max3f(float a, float b, float c) {
  float r;
  asm("v_max3_f32 %0, %1, %2, %3" : "=v"(r) : "v"(a), "v"(b), "v"(c));
  return r;
}

__device__ __forceinline__ void gload16(const void* g, void* l) {
  __builtin_amdgcn_global_load_lds(
      (const __attribute__((address_space(1))) void*)g,
      (__attribute__((address_space(3))) void*)l, 16, 0, 0);
}

// ------------------------------------------- fused convert x + transpose W
__global__ void k_prep(const float* __restrict__ x, unsigned short* __restrict__ xbf,
                       const float* __restrict__ Wq, const float* __restrict__ Wk,
                       const float* __restrict__ Wv, const float* __restrict__ Wo,
                       unsigned short* __restrict__ wt_qkv, unsigned short* __restrict__ wt_o) {
  __shared__ float tls[64][65];
  if (blockIdx.x < 4096) {
    int i = (blockIdx.x * 256 + threadIdx.x) * 4;
    float4 v = *(const float4*)(x + i);
    us4v o;
    o[0] = f2bf(v.x); o[1] = f2bf(v.y); o[2] = f2bf(v.z); o[3] = f2bf(v.w);
    *(us4v*)(xbf + i) = o;
    return;
  }
  int bid = blockIdx.x - 4096;
  int mat = bid >> 8;
  int tile = bid & 255;
  int tk = tile >> 4, tn = tile & 15;
  const float* W = (mat == 0) ? Wq : (mat == 1) ? Wk : (mat == 2) ? Wv : Wo;
  int t = threadIdx.x;
  int lr = t >> 2;
  int lc0 = (t & 3) * 16;
  const float* src = W + (size_t)(tk * 64 + lr) * 1024 + tn * 64 + lc0;
#pragma unroll
  for (int j = 0; j < 16; j += 4) {
    float4 v = *(const float4*)(src + j);
    tls[lr][lc0 + j + 0] = v.x; tls[lr][lc0 + j + 1] = v.y;
    tls[lr][lc0 + j + 2] = v.z; tls[lr][lc0 + j + 3] = v.w;
  }
  __syncthreads();
  float scale = (mat == 0) ? 0.18033688f : 1.0f;  // 0.125 * 1/ln2
  int nr = t >> 2, kc0 = (t & 3) * 16;
  unsigned short* dst = ((mat < 3) ? (wt_qkv + (size_t)(mat * 1024 + tn * 64 + nr) * 1024)
                                   : (wt_o + (size_t)(tn * 64 + nr) * 1024)) + tk * 64 + kc0;
  us8v o0, o1;
#pragma unroll
  for (int j = 0; j < 8; j++) o0[j] = f2bf(tls[kc0 + j][nr] * scale);
#pragma unroll
  for (int j = 0; j < 8; j++) o1[j] = f2bf(tls[kc0 + 8 + j][nr] * scale);
  *(us8v*)(dst) = o0;
  *(us8v*)(dst + 8) = o1;
}

// --------------------------------------------------------------- QKV GEMM
// BK=32, FOUR-stage rotation (64KB, 2 WG/CU) -- R21 proven-best (120.47us
// total; R22's 5-stage was neutral => latency-cover exhausted at depth 2).
// sched_barrier(0) pins removed from the K-loop: the asm waitcnt/barrier
// "memory" clobbers already order all LDS/VMEM ops, and order-pinning is
// neutral-to-harmful (m137/m141).
__global__ __launch_bounds__(256) void k_gemm0(const unsigned short* __restrict__ A,
                                               const unsigned short* __restrict__ Bt,
                                               unsigned short* __restrict__ qklin,
                                               unsigned short* __restrict__ vt,
                                               float* __restrict__ vmean) {
  __shared__ unsigned short smem[8 * 128 * 32];  // 64KB: A bufs 0-3, B bufs 0-3
#define SA(b_) (smem + (b_)*4096)
#define SB(b_) (smem + 16384 + (b_)*4096)
  const int K = 1024;
  const int NT = K / 32;
  int bid = blockIdx.x;
  int xcd = bid & 7, local = bid >> 3;
  int m0 = ((xcd >> 1) * 8 + (local & 7)) * 128;   // R20 chunking
  int n0 = ((xcd & 1) * 12 + (local >> 3)) * 128;
  int tid = threadIdx.x, lane = tid & 63, w = tid >> 6;
  int wm = w >> 1, wn = w & 1;
  int g = lane >> 4, c0 = lane & 15;
  int rrel = lane >> 2;
  int gran = lane & 3;
  int rsw = (rrel >> 1) & 3;
  int csw = (c0 >> 1) & 3;
  f4v acc[4][4];
#pragma unroll
  for (int mi = 0; mi < 4; mi++)
#pragma unroll
    for (int ni = 0; ni < 4; ni++) acc[mi][ni] = (f4v){0.f, 0.f, 0.f, 0.f};

#define STAGE(kt_, buf_)                                                        \
  do {                                                                          \
    int koff = (kt_)*32;                                                        \
    _Pragma("unroll") for (int i = 0; i < 2; i++) {                             \
      int r = 32 * w + 16 * i + rrel;                                           \
      gload16(A + (size_t)(m0 + r) * K + koff + 8 * (gran ^ rsw),               \
              (void*)(SA(buf_) + (32 * w + 16 * i) * 32));                      \
      gload16(Bt + (size_t)(n0 + r) * K + koff + 8 * (gran ^ rsw),              \
              (void*)(SB(buf_) + (32 * w + 16 * i) * 32));                      \
    }                                                                           \
  } while (0)

  // prologue: 3 tiles in flight (12 loads/wave); retire S(0) -> vmcnt(8)
  STAGE(0, 0);
  STAGE(1, 1);
  STAGE(2, 2);
  asm volatile("s_waitcnt vmcnt(8)" ::: "memory");
  __builtin_amdgcn_s_barrier();

  for (int kt = 0; kt < NT; ++kt) {
    int cur = kt & 3;
    if (kt + 3 < NT) STAGE(kt + 3, (kt + 3) & 3);
    s8v af[4], bfr[4];
#pragma unroll
    for (int mi = 0; mi < 4; mi++) {
      int row = 64 * wm + 16 * mi + c0;
      af[mi] = *(const s8v*)(SA(cur) + row * 32 + 8 * (g ^ csw));
    }
#pragma unroll
    for (int ni = 0; ni < 4; ni++) {
      int row = 64 * wn + 16 * ni + c0;
      bfr[ni] = *(const s8v*)(SB(cur) + row * 32 + 8 * (g ^ csw));
    }
#pragma unroll
    for (int mi = 0; mi < 4; mi++)
#pragma unroll
      for (int ni = 0; ni < 4; ni++)
        acc[mi][ni] = __builtin_amdgcn_mfma_f32_16x16x32_bf16(af[mi], bfr[ni], acc[mi][ni], 0, 0, 0);
    if (kt + 1 < NT) {
      if (kt + 3 < NT) {
        asm volatile("s_waitcnt vmcnt(8)" ::: "memory");  // retire S(kt+1)
      } else if (kt + 2 < NT) {
        asm volatile("s_waitcnt vmcnt(4)" ::: "memory");
      } else {
        asm volatile("s_waitcnt vmcnt(0)" ::: "memory");
      }
      __builtin_amdgcn_s_barrier();
    }
  }
#undef STAGE

  if (n0 < 2048) {
#pragma unroll
    for (int mi = 0; mi < 4; mi++)
#pragma unroll
      for (int ni = 0; ni < 4; ni++)
#pragma unroll
        for (int r = 0; r < 4; r++) {
          int m = m0 + 64 * wm + 16 * mi + 4 * g + r;
          int n = n0 + 64 * wn + 16 * ni + c0;
          qklin[(size_t)m * 2048 + n] = f2bf(acc[mi][ni][r]);
        }
  } else {
    int bb = m0 >> 11;
#pragma unroll
    for (int ni = 0; ni < 4; ni++) {
      float s = 0.f;
#pragma unroll
      for (int mi = 0; mi < 4; mi++)
#pragma unroll
        for (int r = 0; r < 4; r++) s += acc[mi][ni][r];
      s += __shfl_xor(s, 16);
      s += __shfl_xor(s, 32);
      if ((lane >> 4) == 0) {
        int n = n0 + 64 * wn + 16 * ni + c0;
        int hh = (n - 2048) >> 6, dk = n & 63;
        atomicAdd(vmean + (bb * 16 + hh) * 64 + dk, s);
      }
    }
    const int PAD = 132;
    unsigned short* tl = smem;
    __syncthreads();
#pragma unroll
    for (int mi = 0; mi < 4; mi++)
#pragma unroll
      for (int ni = 0; ni < 4; ni++) {
        int nloc = 64 * wn + 16 * ni + c0;
        int m4 = 64 * wm + 16 * mi + 4 * g;
        us4v pk;
#pragma unroll
        for (int r = 0; r < 4; r++) pk[r] = f2bf(acc[mi][ni][r]);
        *(us4v*)(tl + nloc * PAD + m4) = pk;
      }
    __syncthreads();
    int row = tid >> 1, half = tid & 1;
    int n = n0 + row;
    int hh = (n - 2048) >> 6, dk = n & 63;
    int s0 = (m0 & 2047) + 64 * half;
    unsigned short* dstp = vt + (size_t)((bb * 16 + hh) * 64 + dk) * 2048 + s0;
    const unsigned short* srcp = tl + row * PAD + 64 * half;
#pragma unroll
    for (int j = 0; j < 8; j++) {
      us4v lo = *(const us4v*)(srcp + 8 * j);
      us4v hi = *(const us4v*)(srcp + 8 * j + 4);
      us8v v8;
      v8[0] = lo[0]; v8[1] = lo[1]; v8[2] = lo[2]; v8[3] = lo[3];
      v8[4] = hi[0]; v8[5] = hi[1]; v8[6] = hi[2]; v8[7] = hi[3];
      *(us8v*)(dstp + 8 * j) = v8;
    }
  }
#undef SA
#undef SB
}

// ------------------------------------------------------------ output GEMM
// 64x64 tiles, BK=64, 2-buf, 32KB LDS, 4 WG/CU (R20, proven).
__global__ __launch_bounds__(256) void k_gemm1(const unsigned short* __restrict__ A,
                                               const unsigned short* __restrict__ Bt,
                                               const float* __restrict__ bias,
                                               float* __restrict__ out) {
  __shared__ unsigned short lds_a[2][64 * 64];
  __shared__ unsigned short lds_b[2][64 * 64];
  const int K = 1024;
  const int NT = K / 64;
  int bid = blockIdx.x;
  int xcd = bid & 7, local = bid >> 3;
  int m0 = (xcd * 8 + (local & 7)) * 64;
  int n0 = (local >> 3) * 64;
  int tid = threadIdx.x, lane = tid & 63, w = tid >> 6;
  int wm = w >> 1, wn = w & 1;
  int g = lane >> 4, c0 = lane & 15;
  int rrel = lane >> 3;
  int gran = lane & 7;
  f4v acc[2][2];
#pragma unroll
  for (int mi = 0; mi < 2; mi++)
#pragma unroll
    for (int ni = 0; ni < 2; ni++) acc[mi][ni] = (f4v){0.f, 0.f, 0.f, 0.f};

#define STAGE1(kt_, buf_)                                                       \
  do {                                                                          \
    int koff = (kt_)*64;                                                        \
    _Pragma("unroll") for (int i = 0; i < 2; i++) {                             \
      int r = 16 * w + 8 * i + rrel;                                            \
      gload16(A + (size_t)(m0 + r) * K + koff + 8 * (gran ^ rrel),              \
              (void*)(lds_a[buf_] + (16 * w + 8 * i) * 64));                    \
      gload16(Bt + (size_t)(n0 + r) * K + koff + 8 * (gran ^ rrel),             \
              (void*)(lds_b[buf_] + (16 * w + 8 * i) * 64));                    \
    }                                                                           \
  } while (0)

  STAGE1(0, 0);
  __syncthreads();

  for (int kt = 0; kt < NT; ++kt) {
    int cur = kt & 1;
    if (kt + 1 < NT) STAGE1(kt + 1, cur ^ 1);
#pragma unroll
    for (int c = 0; c < 2; c++) {
      s8v af[2], bfr[2];
#pragma unroll
      for (int mi = 0; mi < 2; mi++) {
        int row = 32 * wm + 16 * mi + c0;
        af[mi] = *(const s8v*)(lds_a[cur] + row * 64 + 8 * ((g + 4 * c) ^ (c0 & 7)));
      }
#pragma unroll
      for (int ni = 0; ni < 2; ni++) {
        int row = 32 * wn + 16 * ni + c0;
        bfr[ni] = *(const s8v*)(lds_b[cur] + row * 64 + 8 * ((g + 4 * c) ^ (c0 & 7)));
      }
#pragma unroll
      for (int mi = 0; mi < 2; mi++)
#pragma unroll
        for (int ni = 0; ni < 2; ni++)
          acc[mi][ni] = __builtin_amdgcn_mfma_f32_16x16x32_bf16(af[mi], bfr[ni], acc[mi][ni], 0, 0, 0);
    }
    __syncthreads();
  }
#undef STAGE1

#pragma unroll
  for (int mi = 0; mi < 2; mi++)
#pragma unroll
    for (int ni = 0; ni < 2; ni++)
#pragma unroll
      for (int r = 0; r < 4; r++) {
        int m = m0 + 32 * wm + 16 * mi + 4 * g + r;
        int n = n0 + 32 * wn + 16 * ni + c0;
        out[(size_t)m * 1024 + n] = acc[mi][ni][r] + bias[n];
      }
}

// ------------------------------------------------------------ flash attention
// R19 version (proven 54.1us): pair-unrolled K-loop, compile-time cur/HASNEXT,
// causal mask only on the last tile, MFMA row-sum for l, v_max3 tree,
// defer-max (T13), exp2 softmax, counted vmcnt(5).
__global__ __launch_bounds__(256) void k_attn(const unsigned short* __restrict__ qklin,
                                              const unsigned short* __restrict__ vt,
                                              const int* __restrict__ kpm,
                                              const float* __restrict__ vmean,
                                              unsigned short* __restrict__ ctx) {
  __shared__ unsigned short lds_k[2][64 * 64];
  __shared__ unsigned short lds_v[2][64 * 64];
  __shared__ unsigned short p_lds[4][16 * 64];
  int wg = blockIdx.x;
  int w5 = wg >> 5, bh = wg & 31;
  int qt = (w5 < 8) ? 31 - w5 : (w5 < 16) ? w5 - 8 : (w5 < 24) ? 39 - w5 : w5 - 16;
  int b = bh >> 4, h = bh & 15;
  int tid = threadIdx.x, lane = tid & 63, w = tid >> 6;
  int g = lane >> 4, c0 = lane & 15;
  int q0 = qt * 64 + w * 16;
  unsigned short* pl = p_lds[w];
  int rrel = lane >> 3, gran = lane & 7;

  const unsigned short* ksrc0 = qklin + (size_t)(b * NS) * 2048 + 1024 + h * 64;
  const unsigned short* vsrc0 = vt + (size_t)(bh * 64) * 2048;

  const unsigned short* qbase = qklin + (size_t)(b * NS + q0 + c0) * 2048 + h * 64 + 8 * g;
  s8v qf0 = *(const s8v*)(qbase);
  s8v qf1 = *(const s8v*)(qbase + 32);

  const uint32_t one2 = 0x3F803F80u;
  u4v onesw = {one2, one2, one2, one2};
  s8v ones = __builtin_bit_cast(s8v, onesw);

  f4v cacc[4];
#pragma unroll
  for (int d = 0; d < 4; d++) cacc[d] = (f4v){0.f, 0.f, 0.f, 0.f};
  f4v lsum = (f4v){0.f, 0.f, 0.f, 0.f};
  float m_s = -1e30f;
  int qrow = q0 + c0;

#define STAGEKV(it_, buf_)                                                      \
  do {                                                                          \
    int kb_ = (it_)*64;                                                         \
    _Pragma("unroll") for (int i = 0; i < 2; i++) {                             \
      int r = 16 * w + 8 * i + rrel;                                            \
      gload16(ksrc0 + (size_t)(kb_ + r) * 2048 + 8 * (gran ^ rrel),             \
              (void*)(lds_k[buf_] + (16 * w + 8 * i) * 64));                    \
      gload16(vsrc0 + (size_t)r * 2048 + kb_ + 8 * (gran ^ rrel),               \
              (void*)(lds_v[buf_] + (16 * w + 8 * i) * 64));                    \
    }                                                                           \
  } while (0)

#define ATTN_BODY(CUR, HASNEXT, FULLC)                                          \
  {                                                                             \
    int kb = it * 64;                                                           \
    int kp_next = 0;                                                            \
    if (HASNEXT) {                                                              \
      STAGEKV(it + 1, CUR ^ 1);                                                 \
      kp_next = kpm[b * NS + (it + 1) * 64 + lane];                             \
      asm volatile("s_waitcnt vmcnt(5)" ::: "memory");                          \
    } else {                                                                    \
      asm volatile("s_waitcnt vmcnt(0)" ::: "memory");                          \
    }                                                                           \
    __builtin_amdgcn_s_barrier();                                               \
    __builtin_amdgcn_sched_barrier(0);                                          \
    uint64_t padmask = __ballot(kp_cur != 0);                                   \
    f4v sacc[4];                                                                \
    _Pragma("unroll") for (int t = 0; t < 4; t++) {                             \
      int row = 16 * t + c0;                                                    \
      s8v kf0 = *(const s8v*)(lds_k[CUR] + row * 64 + 8 * (g ^ (c0 & 7)));      \
      s8v kf1 = *(const s8v*)(lds_k[CUR] + row * 64 + 8 * ((4 + g) ^ (c0 & 7)));\
      f4v z = (f4v){0.f, 0.f, 0.f, 0.f};                                        \
      z = __builtin_amdgcn_mfma_f32_16x16x32_bf16(kf0, qf0, z, 0, 0, 0);        \
      z = __builtin_amdgcn_mfma_f32_16x16x32_bf16(kf1, qf1, z, 0, 0, 0);        \
      sacc[t] = z;                                                              \
    }                                                                           \
    uint64_t valid;                                                             \
    if (FULLC) {                                                                \
      valid = ~padmask;                                                         \
    } else {                                                                    \
      int thr = qrow - kb;                                                      \
      uint64_t cmask = (thr >= 63) ? ~0ull : ((2ull << thr) - 1ull);            \
      valid = cmask & ~padmask;                                                 \
    }                                                                           \
    uint32_t vlo = (uint32_t)valid, vhi = (uint32_t)(valid >> 32);              \
    float p[4][4];                                                              \
    _Pragma("unroll") for (int t = 0; t < 4; t++) {                             \
      uint32_t half = (t & 2) ? vhi : vlo;                                      \
      uint32_t nib = (half >> (16 * (t & 1) + 4 * g)) & 0xFu;                   \
      _Pragma("unroll") for (int r = 0; r < 4; r++) {                           \
        float s = sacc[t][r];                                                   \
        s = ((nib >> r) & 1u) ? s : -1e30f;                                     \
        p[t][r] = s;                                                            \
      }                                                                         \
    }                                                                           \
    float a0 = max3f(p[0][0], p[0][1], p[0][2]);                                \
    float a1 = max3f(p[0][3], p[1][0], p[1][1]);                                \
    float a2 = max3f(p[1][2], p[1][3], p[2][0]);                                \
    float a3 = max3f(p[2][1], p[2][2], p[2][3]);                                \
    float a4 = max3f(p[3][0], p[3][1], p[3][2]);                                \
    float mx = fmaxf(max3f(a0, a1, a2), max3f(a3, a4, p[3][3]));                \
    mx = fmaxf(mx, __shfl_xor(mx, 16));                                         \
    mx = fmaxf(mx, __shfl_xor(mx, 32));                                         \
    if (!__all(mx <= m_s + 11.0f)) {                                            \
      float mnew = fmaxf(m_s, mx);                                              \
      float a = __builtin_exp2f(m_s - mnew);                                    \
      m_s = mnew;                                                               \
      int ybase = 20 * g;                                                       \
      _Pragma("unroll") for (int r = 0; r < 4; r++) {                           \
        float ar = __shfl(a, ybase + r);                                        \
        lsum[r] *= ar;                                                          \
        _Pragma("unroll") for (int d = 0; d < 4; d++) cacc[d][r] *= ar;         \
      }                                                                         \
    }                                                                           \
    _Pragma("unroll") for (int t = 0; t < 4; t++)                               \
      _Pragma("unroll") for (int r = 0; r < 4; r++)                             \
        p[t][r] = __builtin_exp2f(p[t][r] - m_s);                               \
    _Pragma("unroll") for (int t = 0; t < 4; t++) {                             \
      u2v pk;                                                                   \
      pk[0] = cvtpk(p[t][0], p[t][1]);                                          \
      pk[1] = cvtpk(p[t][2], p[t][3]);                                          \
      int gr = (2 * t + (g >> 1)) ^ (c0 & 7);                                   \
      *(u2v*)((char*)pl + c0 * 128 + gr * 16 + 8 * (g & 1)) = pk;               \
    }                                                                           \
    asm volatile("s_waitcnt lgkmcnt(0)" ::: "memory");                          \
    __builtin_amdgcn_sched_barrier(0);                                          \
    _Pragma("unroll") for (int c = 0; c < 2; c++) {                             \
      int off = c0 * 128 + 16 * g + 64 * c;                                     \
      off ^= (c0 & 7) << 4;                                                     \
      s8v pf = *(const s8v*)((const char*)pl + off);                            \
      _Pragma("unroll") for (int d = 0; d < 4; d++) {                           \
        int row = 16 * d + c0;                                                  \
        s8v vf = *(const s8v*)(lds_v[CUR] + row * 64 + 8 * ((4 * c + g) ^ (c0 & 7))); \
        cacc[d] = __builtin_amdgcn_mfma_f32_16x16x32_bf16(pf, vf, cacc[d], 0, 0, 0);  \
      }                                                                         \
      lsum = __builtin_amdgcn_mfma_f32_16x16x32_bf16(pf, ones, lsum, 0, 0, 0);  \
    }                                                                           \
    __builtin_amdgcn_s_barrier();                                               \
    __builtin_amdgcn_sched_barrier(0);                                          \
    kp_cur = kp_next;                                                           \
  }

  STAGEKV(0, 0);
  int kp_cur = kpm[b * NS + lane];

  int it = 0;
  while (it + 1 < qt) {
    ATTN_BODY(0, 1, 1);
    it++;
    ATTN_BODY(1, 1, 1);
    it++;
  }
  if (qt & 1) {
    ATTN_BODY(0, 1, 1);
    it++;
    ATTN_BODY(1, 0, 0);
  } else {
    ATTN_BODY(0, 0, 0);
  }
#undef ATTN_BODY
#undef STAGEKV

  float mq[4];
  {
    int ybase = 20 * g;
#pragma unroll
    for (int r = 0; r < 4; r++) mq[r] = __shfl(m_s, ybase + r);
  }
#pragma unroll
  for (int d = 0; d < 4; d++)
#pragma unroll
    for (int r = 0; r < 4; r++) {
      int q = q0 + 4 * g + r;
      float l = (mq[r] > -1e29f) ? lsum[r] : 0.f;
      float v = (l > 0.f) ? cacc[d][r] / l
                          : vmean[bh * 64 + 16 * d + c0] * (1.0f / 2048.0f);
      ctx[(size_t)(b * NS + q) * ND + h * 64 + 16 * d + c0] = f2bf(v);
    }
}

// ----------------------------------------------------------------------------
extern "C" void kernel_launch(void* const* d_in, const int* in_sizes, int n_in,
                              void* d_out, int out_size, void* d_ws, size_t ws_size,
                              hipStream_t stream) {
  const float* x  = (const float*)d_in[0];
  const int* kpm  = (const int*)d_in[2];
  const float* Wq = (const float*)d_in[3];
  const float* Wk = (const float*)d_in[4];
  const float* Wv = (const float*)d_in[5];
  const float* Wo = (const float*)d_in[6];
  const float* bo = (const float*)d_in[7];

  char* ws = (char*)d_ws;
  unsigned short* xbf   = (unsigned short*)(ws);
  unsigned short* wtqkv = (unsigned short*)(ws + 8u * 1024 * 1024);
  unsigned short* wto   = (unsigned short*)(ws + 14u * 1024 * 1024);
  unsigned short* vt    = (unsigned short*)(ws + 16u * 1024 * 1024);
  float* vmean          = (float*)(ws + 24u * 1024 * 1024);
  unsigned short* ctx   = xbf;
  unsigned short* qklin = (unsigned short*)d_out;

  hipMemsetAsync(vmean, 0, 2048 * sizeof(float), stream);
  k_prep<<<5120, 256, 0, stream>>>(x, xbf, Wq, Wk, Wv, Wo, wtqkv, wto);
  k_gemm0<<<768, 256, 0, stream>>>(xbf, wtqkv, qklin, vt, vmean);
  k_attn<<<1024, 256, 0, stream>>>(qklin, vt, kpm, vmean, ctx);
  k_gemm1<<<1024, 256, 0, stream>>>(ctx, wto, bo, (float*)d_out);
}